// Round 9
// baseline (212.147 us; speedup 1.0000x reference)
//
#include <hip/hip_runtime.h>

// Problem: B=16,C=64,H=32,W=32 -> N=16384 tokens; K=8192 codes.
#define DECAYF 0.99f
#define OMDF   0.01f
#define TAU    1.0e-2f    // > quantize step (<=7.6e-4) + split-bf16 err (<=5e-4), x8 margin

typedef unsigned int u32;
typedef unsigned long long u64;
typedef __attribute__((ext_vector_type(8))) short bf16x8;   // 8 bf16 (4 VGPRs)
typedef __attribute__((ext_vector_type(4))) float f32x4;    // MFMA 16x16 acc

// ws layout (bytes)
#define EN_OFF     0              // en[8192] f32: 0.5*||e||^2
#define EFRAG_OFF  32768          // 4 MB frag-ordered bf16 hi/lo of emb (16x16x32 layout)
#define BEST1_OFF  4227072        // u64 [16384][8] per-(token,slice) best (enc)
#define BEST2_OFF  5275648        // f32 [16384][8] per-(token,slice) 2nd-best score
#define IDX_OFF    5799936        // i32 [16384] final indices
#define LIST_OFF   5865472        // i32 [16384] ambiguous-token list
#define CNT_OFF    5931008        // i32 count ; +4: f32 nsum (partial: 0.99*sum(cs_in))
#define CELL_OFF   5931016        // u64 [16384] exact-score cells for listed tokens
#define DONE_OFF   6062088        // i32 [16384] fixup slice-completion counters

__device__ __forceinline__ u64 enc_pair(float s, int idx) {
  u32 u = __float_as_uint(s);
  u = (u & 0x80000000u) ? ~u : (u | 0x80000000u);   // order-preserving
  return ((u64)u << 32) | (u32)(~idx);              // ~idx: ties -> min idx
}
__device__ __forceinline__ float dec_score(u64 e) {
  u32 u = (u32)(e >> 32);
  u = (u & 0x80000000u) ? (u & 0x7fffffffu) : ~u;
  return __uint_as_float(u);
}
__device__ __forceinline__ int dec_idx(u64 e) { return (int)(~(u32)e); }
__device__ __forceinline__ unsigned short f2bf(float f) {  // f32 -> bf16 RNE
  u32 u = __float_as_uint(f);
  u += 0x7fffu + ((u >> 16) & 1u);
  return (unsigned short)(u >> 16);
}

// ---- fused prep: en + eprep (16x16x32 frag layout) + EMA init ------------
// efrag layout: [slice8][tile16][cb4][kstep2][split2][ (kq*16+n)*16 + j*2 ]
// (per-frag 1024B: lane l=kq*16+n reads 16B at l*16; B[n][k=kq*8+j])
__global__ __launch_bounds__(256) void k_prep(const float* __restrict__ emb,
                                              const float* __restrict__ cs_in,
                                              const float* __restrict__ avg_in,
                                              float* __restrict__ en,
                                              unsigned char* __restrict__ efrag,
                                              float* __restrict__ out4,
                                              float* __restrict__ out5,
                                              float* __restrict__ nsum) {
  int tid = blockIdx.x * 256 + threadIdx.x;   // 264192 total
  if (tid < 131072) {                          // eprep + en: one float4 of emb
    int kcode = tid >> 4, q = tid & 15;
    int c0 = q * 4;
    float4 v = ((const float4*)emb)[tid];
    int slice = kcode >> 10, tile = (kcode >> 6) & 15;
    int cb = (kcode >> 4) & 3, n = kcode & 15;
    int kstep = c0 >> 5, kq = (c0 >> 3) & 3, jj = c0 & 7;   // jj in {0,4}
    ushort4 hi, lo;
    hi.x = f2bf(v.x); lo.x = f2bf(v.x - __uint_as_float((u32)hi.x << 16));
    hi.y = f2bf(v.y); lo.y = f2bf(v.y - __uint_as_float((u32)hi.y << 16));
    hi.z = f2bf(v.z); lo.z = f2bf(v.z - __uint_as_float((u32)hi.z << 16));
    hi.w = f2bf(v.w); lo.w = f2bf(v.w - __uint_as_float((u32)hi.w << 16));
    size_t base = (size_t)slice * 262144 + (size_t)tile * 16384
                + (size_t)cb * 4096 + (size_t)kstep * 2048;
    size_t woff = (size_t)((kq * 16 + n) * 16 + jj * 2);
    *(ushort4*)(efrag + base + woff)        = hi;   // split 0 (hi)
    *(ushort4*)(efrag + base + 1024 + woff) = lo;   // split 1 (lo)
    float s = v.x * v.x + v.y * v.y + v.z * v.z + v.w * v.w;  // R1 bit-exact en
    s += __shfl_xor(s, 1, 16);
    s += __shfl_xor(s, 2, 16);
    s += __shfl_xor(s, 4, 16);
    s += __shfl_xor(s, 8, 16);
    if (q == 0) en[kcode] = 0.5f * s;
  } else if (tid < 262144) {                   // 0.99 * embedding_avg
    int t = tid - 131072;
    float4 v = ((const float4*)avg_in)[t];
    v.x *= DECAYF; v.y *= DECAYF; v.z *= DECAYF; v.w *= DECAYF;
    ((float4*)out5)[t] = v;
  } else {                                     // 0.99 * cluster_size + partial n
    int t = tid - 262144;                      // 2048 float4s, whole blocks
    float4 v = ((const float4*)cs_in)[t];
    v.x *= DECAYF; v.y *= DECAYF; v.z *= DECAYF; v.w *= DECAYF;
    ((float4*)out4)[t] = v;
    float s = v.x + v.y + v.z + v.w;           // already x0.99
    s += __shfl_xor(s, 1, 64);
    s += __shfl_xor(s, 2, 64);
    s += __shfl_xor(s, 4, 64);
    s += __shfl_xor(s, 8, 64);
    s += __shfl_xor(s, 16, 64);
    s += __shfl_xor(s, 32, 64);
    if ((threadIdx.x & 63) == 0) atomicAdd(nsum, s);
  }
}

// ---- MFMA argmin: 16x16x32 bf16 — low register pressure, no spills -------
// wave = 16 tokens; block = 4 waves (64 tokens) x 1 slice; grid 2048.
// acc 4 regs; b1/b2 shared across the 4 code-blocks of each 64-code tile.
__global__ __launch_bounds__(256, 4) void k_argmin_mfma(
    const float* __restrict__ z_e, const unsigned char* __restrict__ efrag,
    const float* __restrict__ en, u64* __restrict__ best1,
    float* __restrict__ best2) {
  const int tb = blockIdx.x >> 3;            // 64-token group
  const int sl = blockIdx.x & 7;             // K-slice (1024 codes)
  const int wave = threadIdx.x >> 6, lane = threadIdx.x & 63;
  const int n16 = lane & 15, kq = lane >> 4;
  const int token0 = tb * 64 + wave * 16;
  const int scb = sl * 1024;

  // A-frags: A[m=lane&15][k=(lane>>4)*8+j], K=64 -> 2 ksteps, hi/lo split
  bf16x8 ahi[2], alo[2];
  {
    const int token = token0 + n16;
    const float* zp = z_e + ((size_t)(token >> 10) << 16) + (token & 1023);
#pragma unroll
    for (int ks = 0; ks < 2; ++ks) {
#pragma unroll
      for (int j = 0; j < 8; ++j) {
        int c = ks * 32 + kq * 8 + j;
        float x = zp[(size_t)c << 10];
        unsigned short xh = f2bf(x);
        ahi[ks][j] = (short)xh;
        alo[ks][j] = (short)f2bf(x - __uint_as_float((u32)xh << 16));
      }
    }
  }
  float b1[4], b2[4];
#pragma unroll
  for (int r = 0; r < 4; ++r) { b1[r] = -3.0e38f; b2[r] = -3.0e38f; }

  const unsigned char* pb = efrag + (size_t)sl * 262144 + (size_t)lane * 16;

  for (int t = 0; t < 16; ++t) {             // 16 tiles x 64 codes
    const unsigned char* bt = pb + (size_t)t * 16384;
#pragma unroll
    for (int cb = 0; cb < 4; ++cb) {
      const unsigned char* bc = bt + (size_t)cb * 4096;
      bf16x8 bh0 = *(const bf16x8*)(bc);
      bf16x8 bl0 = *(const bf16x8*)(bc + 1024);
      bf16x8 bh1 = *(const bf16x8*)(bc + 2048);
      bf16x8 bl1 = *(const bf16x8*)(bc + 3072);
      float enl = en[scb + t * 64 + cb * 16 + n16];
      f32x4 acc;
#pragma unroll
      for (int r = 0; r < 4; ++r) acc[r] = -enl;   // fold -0.5||e||^2
      acc = __builtin_amdgcn_mfma_f32_16x16x32_bf16(ahi[0], bh0, acc, 0, 0, 0);
      acc = __builtin_amdgcn_mfma_f32_16x16x32_bf16(alo[0], bh0, acc, 0, 0, 0);
      acc = __builtin_amdgcn_mfma_f32_16x16x32_bf16(ahi[0], bl0, acc, 0, 0, 0);
      acc = __builtin_amdgcn_mfma_f32_16x16x32_bf16(ahi[1], bh1, acc, 0, 0, 0);
      acc = __builtin_amdgcn_mfma_f32_16x16x32_bf16(alo[1], bh1, acc, 0, 0, 0);
      acc = __builtin_amdgcn_mfma_f32_16x16x32_bf16(ahi[1], bl1, acc, 0, 0, 0);
      const u32 id6 = (u32)(63 - (t * 4 + cb));    // sub-idx, low 6 mantissa bits
#pragma unroll
      for (int r = 0; r < 4; ++r) {
        float f = __uint_as_float((__float_as_uint(acc[r]) & 0xFFFFFFC0u) | id6);
        b2[r] = __builtin_amdgcn_fmed3f(f, b1[r], b2[r]);   // max(b2,min(b1,f))
        b1[r] = fmaxf(b1[r], f);
      }
    }
  }

  // merge over the 16 code-class lanes (xor 1,2,4,8 keeps kq constant)
  int mi[4];
#pragma unroll
  for (int r = 0; r < 4; ++r) mi[r] = n16;
#pragma unroll
  for (int st = 1; st < 16; st <<= 1) {
#pragma unroll
    for (int r = 0; r < 4; ++r) {
      float ob1 = __shfl_xor(b1[r], st, 64);
      float ob2 = __shfl_xor(b2[r], st, 64);
      int omi = __shfl_xor(mi[r], st, 64);
      bool ogt = ob1 > b1[r];            // strict: equal -> quantized tie -> fixup
      b2[r] = fmaxf(fminf(b1[r], ob1), fmaxf(b2[r], ob2));
      mi[r] = ogt ? omi : mi[r];
      b1[r] = fmaxf(b1[r], ob1);
    }
  }
  if (n16 == 0) {    // lanes 0,16,32,48: rows kq*4 + r (C/D row map, m89)
#pragma unroll
    for (int r = 0; r < 4; ++r) {
      int token = token0 + kq * 4 + r;
      int idq = 63 - (int)(__float_as_uint(b1[r]) & 63u);
      int gcode = scb + (idq >> 2) * 64 + (idq & 3) * 16 + mi[r];
      best1[token * 8 + sl] = enc_pair(b1[r], gcode);
      best2[token * 8 + sl] = b2[r];
    }
  }
}

// ---- merge 8 slices, pick top1, flag ambiguous tokens -------------------
__global__ __launch_bounds__(256) void k_resolve(const u64* __restrict__ best1,
                                                 const float* __restrict__ best2,
                                                 int* __restrict__ idxa,
                                                 int* __restrict__ list,
                                                 int* __restrict__ cnt,
                                                 u64* __restrict__ cell,
                                                 int* __restrict__ done) {
  int n = blockIdx.x * 256 + threadIdx.x;   // 16384
  u64 e[8];
  u64 top = 0;
  float second = -3.0e38f;
#pragma unroll
  for (int s = 0; s < 8; ++s) {
    e[s] = best1[n * 8 + s];
    top = e[s] > top ? e[s] : top;
    second = fmaxf(second, best2[n * 8 + s]);
  }
#pragma unroll
  for (int s = 0; s < 8; ++s)
    if (e[s] != top) second = fmaxf(second, dec_score(e[s]));
  idxa[n] = dec_idx(top);
  if (dec_score(top) - second < TAU) {
    int p = atomicAdd(cnt, 1);
    list[p] = n;
    cell[p] = 0;
    done[p] = 0;
  }
}

// ---- exact fp32 rescan, 8 blocks/token; last block writes idxa ----------
__global__ __launch_bounds__(256) void k_fixup(const float* __restrict__ z_e,
                                               const float* __restrict__ emb,
                                               const float* __restrict__ en,
                                               const int* __restrict__ list,
                                               const int* __restrict__ cnt,
                                               u64* __restrict__ cell,
                                               int* __restrict__ done,
                                               int* __restrict__ idxa) {
  __shared__ float sx[64];
  __shared__ u64 red[256];
  int count = *cnt;
  for (int j = blockIdx.x; j < count * 8; j += gridDim.x) {
    int i = j >> 3, slice = j & 7;      // token slot, 1024-code slice
    int n = list[i];
    __syncthreads();
    if (threadIdx.x < 64) {
      sx[threadIdx.x] = z_e[((size_t)(n >> 10) << 16)
                            + ((size_t)threadIdx.x << 10) + (n & 1023)];
    }
    __syncthreads();
    float x[64];
#pragma unroll
    for (int c = 0; c < 64; ++c) x[c] = sx[c];
    int kb = slice * 1024 + threadIdx.x;
    const float4* e = (const float4*)(emb + (size_t)kb * 64);
    float a0 = 0.f, a1 = 0.f, a2 = 0.f, a3 = 0.f;
#pragma unroll
    for (int q = 0; q < 16; ++q) {
      float4 v0 = e[q], v1 = e[q + 4096], v2 = e[q + 8192], v3 = e[q + 12288];
      a0 = fmaf(x[4 * q], v0.x, a0);
      a0 = fmaf(x[4 * q + 1], v0.y, a0);
      a0 = fmaf(x[4 * q + 2], v0.z, a0);
      a0 = fmaf(x[4 * q + 3], v0.w, a0);
      a1 = fmaf(x[4 * q], v1.x, a1);
      a1 = fmaf(x[4 * q + 1], v1.y, a1);
      a1 = fmaf(x[4 * q + 2], v1.z, a1);
      a1 = fmaf(x[4 * q + 3], v1.w, a1);
      a2 = fmaf(x[4 * q], v2.x, a2);
      a2 = fmaf(x[4 * q + 1], v2.y, a2);
      a2 = fmaf(x[4 * q + 2], v2.z, a2);
      a2 = fmaf(x[4 * q + 3], v2.w, a2);
      a3 = fmaf(x[4 * q], v3.x, a3);
      a3 = fmaf(x[4 * q + 1], v3.y, a3);
      a3 = fmaf(x[4 * q + 2], v3.z, a3);
      a3 = fmaf(x[4 * q + 3], v3.w, a3);
    }
    a0 -= en[kb];
    a1 -= en[kb + 256];
    a2 -= en[kb + 512];
    a3 -= en[kb + 768];
    u64 m0 = enc_pair(a0, kb);
    u64 m1 = enc_pair(a1, kb + 256);
    u64 m2 = enc_pair(a2, kb + 512);
    u64 m3 = enc_pair(a3, kb + 768);
    u64 ma = m0 > m1 ? m0 : m1, mb = m2 > m3 ? m2 : m3;
    red[threadIdx.x] = ma > mb ? ma : mb;
    __syncthreads();
    for (int st = 128; st > 0; st >>= 1) {
      if (threadIdx.x < st) {
        u64 o = red[threadIdx.x + st];
        if (o > red[threadIdx.x]) red[threadIdx.x] = o;
      }
      __syncthreads();
    }
    if (threadIdx.x == 0) {
      atomicMax(&cell[i], red[0]);
      __threadfence();                        // max visible before done++
      int old = atomicAdd(&done[i], 1);
      if (old == 7) {                         // last slice: fold k_post in
        u64 v = atomicMax(&cell[i], 0ull);    // atomic read (max with 0)
        idxa[n] = dec_idx(v);
      }
    }
  }
}

// ---- fused scatter (blocks 0..4095) + gather (blocks 4096..5119) ---------
__global__ __launch_bounds__(256) void k_scatter_gather(
    const float* __restrict__ z_e, const float* __restrict__ emb,
    const int* __restrict__ idxa, float* __restrict__ out0,
    float* __restrict__ out1, float* __restrict__ out2,
    float* __restrict__ out4, float* __restrict__ out5) {
  if (blockIdx.x < 4096) {                    // scatter: lane = channel
    int tid = blockIdx.x * 256 + threadIdx.x; // 1M = 16384 tokens x 64 ch
    int n = tid >> 6, c = tid & 63;
    int idx = idxa[n];
    int b = n >> 10, hw = n & 1023;
    float x = z_e[((size_t)b << 16) + ((size_t)c << 10) + hw];
    atomicAdd(out5 + (size_t)idx * 64 + c, OMDF * x);
    if (c == 0) atomicAdd(out4 + idx, OMDF);
  } else {                                    // gather z_q / z_q_st / indices
    int tid = (blockIdx.x - 4096) * 256 + threadIdx.x;  // 262144
    int hw4 = tid & 255;
    int c   = (tid >> 8) & 63;
    int b   = tid >> 14;
    int n0  = (b << 10) + (hw4 << 2);
    size_t off = ((size_t)b << 16) + ((size_t)c << 10) + ((size_t)hw4 << 2);
    float4 z = *(const float4*)(z_e + off);
    int i0 = idxa[n0], i1 = idxa[n0 + 1], i2 = idxa[n0 + 2], i3 = idxa[n0 + 3];
    float4 q;
    q.x = emb[(size_t)i0 * 64 + c];
    q.y = emb[(size_t)i1 * 64 + c];
    q.z = emb[(size_t)i2 * 64 + c];
    q.w = emb[(size_t)i3 * 64 + c];
    float4 st;
    st.x = z.x + (q.x - z.x);
    st.y = z.y + (q.y - z.y);
    st.z = z.z + (q.z - z.z);
    st.w = z.w + (q.w - z.w);
    *(float4*)(out2 + off) = q;
    *(float4*)(out0 + off) = st;
    if (c == 0) {
      float4 f = make_float4((float)i0, (float)i1, (float)i2, (float)i3);
      *(float4*)(out1 + n0) = f;
    }
  }
}

// ---- new_embedding = new_embedding_avg / cs -----------------------------
__global__ __launch_bounds__(256) void k_final(const float* __restrict__ out4,
                                               const float* __restrict__ out5,
                                               const float* __restrict__ nsum,
                                               float* __restrict__ out3) {
  int tid = blockIdx.x * 256 + threadIdx.x;
  int k = tid >> 4;
  double nn  = (double)*nsum + 163.84;        // + 0.01*16384 (counts sum exactly)
  double ncs = (double)out4[k];
  double cs  = (ncs + 1e-5) / (nn + 8192.0 * 1e-5) * nn;
  float inv  = (float)(1.0 / cs);
  float4 v = ((const float4*)out5)[tid];
  v.x *= inv; v.y *= inv; v.z *= inv; v.w *= inv;
  ((float4*)out3)[tid] = v;
}

extern "C" void kernel_launch(void* const* d_in, const int* in_sizes, int n_in,
                              void* d_out, int out_size, void* d_ws, size_t ws_size,
                              hipStream_t stream) {
  const float* z_e    = (const float*)d_in[0];
  const float* emb    = (const float*)d_in[1];
  const float* cs_in  = (const float*)d_in[2];
  const float* avg_in = (const float*)d_in[3];

  float* out  = (float*)d_out;
  float* out0 = out;                    // z_q_st        1048576
  float* out1 = out0 + 1048576;         // indices(f32)  16384
  float* out2 = out1 + 16384;           // z_q           1048576
  float* out3 = out2 + 1048576;         // new_embedding 524288
  float* out4 = out3 + 524288;          // new_cluster   8192
  float* out5 = out4 + 8192;            // new_emb_avg   524288

  char* ws = (char*)d_ws;
  float* en            = (float*)(ws + EN_OFF);
  unsigned char* efrag = (unsigned char*)(ws + EFRAG_OFF);
  u64* best1           = (u64*)(ws + BEST1_OFF);
  float* best2         = (float*)(ws + BEST2_OFF);
  int* idxa            = (int*)(ws + IDX_OFF);
  int* list            = (int*)(ws + LIST_OFF);
  int* cnt             = (int*)(ws + CNT_OFF);
  float* nsum          = (float*)(ws + CNT_OFF + 4);
  u64* cell            = (u64*)(ws + CELL_OFF);
  int* done            = (int*)(ws + DONE_OFF);

  hipMemsetAsync(ws + CNT_OFF, 0, 8, stream);   // cnt + nsum (prep atomicAdds nsum)

  k_prep          <<<1032, 256, 0, stream>>>(emb, cs_in, avg_in, en, efrag,
                                             out4, out5, nsum);
  k_argmin_mfma   <<<2048, 256, 0, stream>>>(z_e, efrag, en, best1, best2);
  k_resolve       <<<64,   256, 0, stream>>>(best1, best2, idxa, list, cnt,
                                             cell, done);
  k_fixup         <<<2048, 256, 0, stream>>>(z_e, emb, en, list, cnt, cell,
                                             done, idxa);
  k_scatter_gather<<<5120, 256, 0, stream>>>(z_e, emb, idxa, out0, out1, out2,
                                             out4, out5);
  k_final         <<<512,  256, 0, stream>>>(out4, out5, nsum, out3);
}

// Round 10
// 206.440 us; speedup vs baseline: 1.0276x; 1.0276x over previous
//
#include <hip/hip_runtime.h>

// Problem: B=16,C=64,H=32,W=32 -> N=16384 tokens; K=8192 codes.
#define DECAYF 0.99f
#define OMDF   0.01f
#define TAU    1.0e-2f    // > quantize step (<=2.4e-4) + split-bf16 err (<=5e-4), x10 margin

typedef unsigned int u32;
typedef unsigned long long u64;
typedef __attribute__((ext_vector_type(8))) short bf16x8;   // 8 bf16 (4 VGPRs)
typedef __attribute__((ext_vector_type(16))) float f32x16;  // MFMA 32x32 acc

// ws layout (bytes)
#define EN_OFF     0              // en[8192] f32: 0.5*||e||^2
#define EFRAG_OFF  32768          // frag-ordered bf16 hi/lo of emb (32x32 layout, 2MB+slack)
#define BEST1_OFF  4227072        // u64 [16384][8] per-(token,slice) best (enc)
#define BEST2_OFF  5275648        // f32 [16384][8] per-(token,slice) 2nd-best score
#define IDX_OFF    5799936        // i32 [16384] final indices
#define LIST_OFF   5865472        // i32 [16384] ambiguous-token list
#define CNT_OFF    5931008        // i32 count ; +4: f32 nsum (partial: 0.99*sum(cs_in))
#define CELL_OFF   5931016        // u64 [16384] exact-score cells for listed tokens
#define DONE_OFF   6062088        // i32 [16384] fixup slice-completion counters

__device__ __forceinline__ u64 enc_pair(float s, int idx) {
  u32 u = __float_as_uint(s);
  u = (u & 0x80000000u) ? ~u : (u | 0x80000000u);   // order-preserving
  return ((u64)u << 32) | (u32)(~idx);              // ~idx: ties -> min idx
}
__device__ __forceinline__ float dec_score(u64 e) {
  u32 u = (u32)(e >> 32);
  u = (u & 0x80000000u) ? (u & 0x7fffffffu) : ~u;
  return __uint_as_float(u);
}
__device__ __forceinline__ int dec_idx(u64 e) { return (int)(~(u32)e); }
__device__ __forceinline__ unsigned short f2bf(float f) {  // f32 -> bf16 RNE
  u32 u = __float_as_uint(f);
  u += 0x7fffu + ((u >> 16) & 1u);
  return (unsigned short)(u >> 16);
}

// ---- fused prep: en (R1 bit-exact) + eprep (32x32 frag layout) + EMA init
// efrag: [tile32][kstep*2+split][h][n32][j] (1024B per kstep-split)
__global__ __launch_bounds__(256) void k_prep(const float* __restrict__ emb,
                                              const float* __restrict__ cs_in,
                                              const float* __restrict__ avg_in,
                                              float* __restrict__ en,
                                              unsigned char* __restrict__ efrag,
                                              float* __restrict__ out4,
                                              float* __restrict__ out5,
                                              float* __restrict__ nsum) {
  int tid = blockIdx.x * 256 + threadIdx.x;   // 264192 total
  if (tid < 131072) {                          // en + eprep: one float4 of emb
    int k = tid >> 4, q = tid & 15;
    float4 v = ((const float4*)emb)[tid];
    int kstep = q >> 2, h = (q >> 1) & 1, j0 = (q & 1) * 4;
    int tile = k >> 5, n32 = k & 31;
    ushort4 hi, lo;
    hi.x = f2bf(v.x); lo.x = f2bf(v.x - __uint_as_float((u32)hi.x << 16));
    hi.y = f2bf(v.y); lo.y = f2bf(v.y - __uint_as_float((u32)hi.y << 16));
    hi.z = f2bf(v.z); lo.z = f2bf(v.z - __uint_as_float((u32)hi.z << 16));
    hi.w = f2bf(v.w); lo.w = f2bf(v.w - __uint_as_float((u32)hi.w << 16));
    size_t off = (size_t)tile * 8192 + (size_t)(kstep * 2) * 1024
               + (size_t)h * 512 + (size_t)n32 * 16 + (size_t)j0 * 2;
    *(ushort4*)(efrag + off)        = hi;   // split 0 (hi)
    *(ushort4*)(efrag + off + 1024) = lo;   // split 1 (lo)
    float s = v.x * v.x + v.y * v.y + v.z * v.z + v.w * v.w;
    s += __shfl_xor(s, 1, 16);
    s += __shfl_xor(s, 2, 16);
    s += __shfl_xor(s, 4, 16);
    s += __shfl_xor(s, 8, 16);
    if (q == 0) en[k] = 0.5f * s;
  } else if (tid < 262144) {                   // 0.99 * embedding_avg
    int t = tid - 131072;
    float4 v = ((const float4*)avg_in)[t];
    v.x *= DECAYF; v.y *= DECAYF; v.z *= DECAYF; v.w *= DECAYF;
    ((float4*)out5)[t] = v;
  } else {                                     // 0.99 * cluster_size + partial n
    int t = tid - 262144;                      // 2048 float4s, whole blocks
    float4 v = ((const float4*)cs_in)[t];
    v.x *= DECAYF; v.y *= DECAYF; v.z *= DECAYF; v.w *= DECAYF;
    ((float4*)out4)[t] = v;
    float s = v.x + v.y + v.z + v.w;           // already x0.99
    s += __shfl_xor(s, 1, 64);
    s += __shfl_xor(s, 2, 64);
    s += __shfl_xor(s, 4, 64);
    s += __shfl_xor(s, 8, 64);
    s += __shfl_xor(s, 16, 64);
    s += __shfl_xor(s, 32, 64);
    if ((threadIdx.x & 63) == 0) atomicAdd(nsum, s);
  }
}

// ---- MFMA argmin: 64 tokens/wave (2 sets) -> B-read traffic halved -------
// block = 4 waves x 64 tokens = 256 tokens; slice = 1024 codes; grid 512.
// dbuf LDS staging; per staged tile both sets' MFMA chains run interleaved.
__global__ __launch_bounds__(256, 2) void k_argmin_mfma(
    const float* __restrict__ z_e, const unsigned char* __restrict__ efrag,
    const float* __restrict__ en, u64* __restrict__ best1,
    float* __restrict__ best2) {
  alignas(16) __shared__ unsigned char sbuf[2][16384];   // dbuf: 64 codes each
  const int tb = blockIdx.x >> 3;            // 256-token group
  const int sl = blockIdx.x & 7;             // K-slice (1024 codes)
  const int wave = threadIdx.x >> 6, lane = threadIdx.x & 63;
  const int h = lane >> 5, m = lane & 31;
  const int tokenA = tb * 256 + wave * 64;   // set A: +0..31, set B: +32..63
  const int scb = sl * 1024;
  const unsigned char* gbase0 = efrag + (size_t)scb * 256;   // 256 B/code

  // prefetch ib=0 before the (long) A-fragment build
#pragma unroll
  for (int it = 0; it < 4; ++it) {
    __builtin_amdgcn_global_load_lds(
        (const __attribute__((address_space(1))) u32*)
            (gbase0 + (size_t)wave * 4096 + it * 1024 + lane * 16),
        (__attribute__((address_space(3))) u32*)(sbuf[0] + wave * 4096 + it * 1024),
        16, 0, 0);
  }

  // A-fragments for both token sets
  bf16x8 ahiA[4], aloA[4], ahiB[4], aloB[4];
  {
    const int tA = tokenA + m, tB = tokenA + 32 + m;
    const float* zpA = z_e + ((size_t)(tA >> 10) << 16) + (tA & 1023);
    const float* zpB = z_e + ((size_t)(tB >> 10) << 16) + (tB & 1023);
#pragma unroll
    for (int ks = 0; ks < 4; ++ks) {
#pragma unroll
      for (int j = 0; j < 8; ++j) {
        int c = ks * 16 + h * 8 + j;
        float xA = zpA[(size_t)c << 10];
        float xB = zpB[(size_t)c << 10];
        unsigned short xhA = f2bf(xA), xhB = f2bf(xB);
        ahiA[ks][j] = (short)xhA;
        aloA[ks][j] = (short)f2bf(xA - __uint_as_float((u32)xhA << 16));
        ahiB[ks][j] = (short)xhB;
        aloB[ks][j] = (short)f2bf(xB - __uint_as_float((u32)xhB << 16));
      }
    }
  }
  float b1A[16], b2A[16], b1B[16], b2B[16];
#pragma unroll
  for (int r = 0; r < 16; ++r) {
    b1A[r] = -3.0e38f; b2A[r] = -3.0e38f;
    b1B[r] = -3.0e38f; b2B[r] = -3.0e38f;
  }

  float en_cur = en[scb + m];                // rolling prefetch, stage t=0

  __syncthreads();                           // ib=0 staged
  for (int ib = 0; ib < 16; ++ib) {
    const int buf = ib & 1;
    if (ib + 1 < 16) {                       // stage next tile into other buf
      const unsigned char* g = gbase0 + (size_t)(ib + 1) * 16384
                             + (size_t)wave * 4096;
#pragma unroll
      for (int it = 0; it < 4; ++it) {
        __builtin_amdgcn_global_load_lds(
            (const __attribute__((address_space(1))) u32*)(g + it * 1024 + lane * 16),
            (__attribute__((address_space(3))) u32*)
                (sbuf[buf ^ 1] + wave * 4096 + it * 1024),
            16, 0, 0);
      }
    }
#pragma unroll
    for (int t32 = 0; t32 < 2; ++t32) {
      const int t = ib * 2 + t32;               // 0..31 sub-tile id in slice
      float en_nxt = (t < 31) ? en[scb + (t + 1) * 32 + m] : 0.f;
      const unsigned char* sb = sbuf[buf] + t32 * 8192 + h * 512 + m * 16;
      bf16x8 bh[4], bl[4];
#pragma unroll
      for (int ks = 0; ks < 4; ++ks) {
        bh[ks] = *(const bf16x8*)(sb + (size_t)(ks * 2 + 0) * 1024);
        bl[ks] = *(const bf16x8*)(sb + (size_t)(ks * 2 + 1) * 1024);
      }
      f32x16 accA, accB;
#pragma unroll
      for (int r = 0; r < 16; ++r) { accA[r] = -en_cur; accB[r] = -en_cur; }
      // two independent MFMA chains interleaved (better issue at low occupancy)
#pragma unroll
      for (int ks = 0; ks < 4; ++ks) {
        accA = __builtin_amdgcn_mfma_f32_32x32x16_bf16(ahiA[ks], bh[ks], accA, 0, 0, 0);
        accB = __builtin_amdgcn_mfma_f32_32x32x16_bf16(ahiB[ks], bh[ks], accB, 0, 0, 0);
        accA = __builtin_amdgcn_mfma_f32_32x32x16_bf16(aloA[ks], bh[ks], accA, 0, 0, 0);
        accB = __builtin_amdgcn_mfma_f32_32x32x16_bf16(aloB[ks], bh[ks], accB, 0, 0, 0);
        accA = __builtin_amdgcn_mfma_f32_32x32x16_bf16(ahiA[ks], bl[ks], accA, 0, 0, 0);
        accB = __builtin_amdgcn_mfma_f32_32x32x16_bf16(ahiB[ks], bl[ks], accB, 0, 0, 0);
      }
      const u32 emb5 = (u32)(31 - t);           // sub-idx in low 5 mantissa bits
#pragma unroll
      for (int r = 0; r < 16; ++r) {
        float fA = __uint_as_float((__float_as_uint(accA[r]) & 0xFFFFFFE0u) | emb5);
        b2A[r] = __builtin_amdgcn_fmed3f(fA, b1A[r], b2A[r]);
        b1A[r] = fmaxf(b1A[r], fA);
        float fB = __uint_as_float((__float_as_uint(accB[r]) & 0xFFFFFFE0u) | emb5);
        b2B[r] = __builtin_amdgcn_fmed3f(fB, b1B[r], b2B[r]);
        b1B[r] = fmaxf(b1B[r], fB);
      }
      en_cur = en_nxt;
    }
    __syncthreads();     // drains next-tile loads; protects buf reuse
  }

  // cross-lane top-2 merge over the 32 code-class lanes, both sets
  int miA[16], miB[16];
#pragma unroll
  for (int r = 0; r < 16; ++r) { miA[r] = m; miB[r] = m; }
#pragma unroll
  for (int st = 1; st < 32; st <<= 1) {
#pragma unroll
    for (int r = 0; r < 16; ++r) {
      float oa1 = __shfl_xor(b1A[r], st, 64);
      float oa2 = __shfl_xor(b2A[r], st, 64);
      int oma = __shfl_xor(miA[r], st, 64);
      bool ga = oa1 > b1A[r];          // strict: equal -> quantized tie -> fixup
      b2A[r] = fmaxf(fminf(b1A[r], oa1), fmaxf(b2A[r], oa2));
      miA[r] = ga ? oma : miA[r];
      b1A[r] = fmaxf(b1A[r], oa1);
      float ob1 = __shfl_xor(b1B[r], st, 64);
      float ob2 = __shfl_xor(b2B[r], st, 64);
      int omb = __shfl_xor(miB[r], st, 64);
      bool gb = ob1 > b1B[r];
      b2B[r] = fmaxf(fminf(b1B[r], ob1), fmaxf(b2B[r], ob2));
      miB[r] = gb ? omb : miB[r];
      b1B[r] = fmaxf(b1B[r], ob1);
    }
  }
  if (m == 0) {     // lanes 0 and 32: 16 token-rows each per set
#pragma unroll
    for (int r = 0; r < 16; ++r) {
      int row = (r & 3) + 8 * (r >> 2) + 4 * h;   // C/D row map [m74/m101]
      int tA = 31 - (int)(__float_as_uint(b1A[r]) & 31u);
      int gA = scb + tA * 32 + miA[r];
      best1[(tokenA + row) * 8 + sl] = enc_pair(b1A[r], gA);
      best2[(tokenA + row) * 8 + sl] = b2A[r];
      int tB = 31 - (int)(__float_as_uint(b1B[r]) & 31u);
      int gB = scb + tB * 32 + miB[r];
      best1[(tokenA + 32 + row) * 8 + sl] = enc_pair(b1B[r], gB);
      best2[(tokenA + 32 + row) * 8 + sl] = b2B[r];
    }
  }
}

// ---- merge 8 slices, pick top1, flag ambiguous tokens -------------------
__global__ __launch_bounds__(256) void k_resolve(const u64* __restrict__ best1,
                                                 const float* __restrict__ best2,
                                                 int* __restrict__ idxa,
                                                 int* __restrict__ list,
                                                 int* __restrict__ cnt,
                                                 u64* __restrict__ cell,
                                                 int* __restrict__ done) {
  int n = blockIdx.x * 256 + threadIdx.x;   // 16384
  u64 e[8];
  u64 top = 0;
  float second = -3.0e38f;
#pragma unroll
  for (int s = 0; s < 8; ++s) {
    e[s] = best1[n * 8 + s];
    top = e[s] > top ? e[s] : top;
    second = fmaxf(second, best2[n * 8 + s]);
  }
#pragma unroll
  for (int s = 0; s < 8; ++s)
    if (e[s] != top) second = fmaxf(second, dec_score(e[s]));
  idxa[n] = dec_idx(top);
  if (dec_score(top) - second < TAU) {
    int p = atomicAdd(cnt, 1);
    list[p] = n;
    cell[p] = 0;
    done[p] = 0;
  }
}

// ---- exact fp32 rescan, 8 blocks/token; last block writes idxa ----------
__global__ __launch_bounds__(256) void k_fixup(const float* __restrict__ z_e,
                                               const float* __restrict__ emb,
                                               const float* __restrict__ en,
                                               const int* __restrict__ list,
                                               const int* __restrict__ cnt,
                                               u64* __restrict__ cell,
                                               int* __restrict__ done,
                                               int* __restrict__ idxa) {
  __shared__ float sx[64];
  __shared__ u64 red[256];
  int count = *cnt;
  for (int j = blockIdx.x; j < count * 8; j += gridDim.x) {
    int i = j >> 3, slice = j & 7;      // token slot, 1024-code slice
    int n = list[i];
    __syncthreads();
    if (threadIdx.x < 64) {
      sx[threadIdx.x] = z_e[((size_t)(n >> 10) << 16)
                            + ((size_t)threadIdx.x << 10) + (n & 1023)];
    }
    __syncthreads();
    float x[64];
#pragma unroll
    for (int c = 0; c < 64; ++c) x[c] = sx[c];
    int kb = slice * 1024 + threadIdx.x;
    const float4* e = (const float4*)(emb + (size_t)kb * 64);
    float a0 = 0.f, a1 = 0.f, a2 = 0.f, a3 = 0.f;
#pragma unroll
    for (int q = 0; q < 16; ++q) {
      float4 v0 = e[q], v1 = e[q + 4096], v2 = e[q + 8192], v3 = e[q + 12288];
      a0 = fmaf(x[4 * q], v0.x, a0);
      a0 = fmaf(x[4 * q + 1], v0.y, a0);
      a0 = fmaf(x[4 * q + 2], v0.z, a0);
      a0 = fmaf(x[4 * q + 3], v0.w, a0);
      a1 = fmaf(x[4 * q], v1.x, a1);
      a1 = fmaf(x[4 * q + 1], v1.y, a1);
      a1 = fmaf(x[4 * q + 2], v1.z, a1);
      a1 = fmaf(x[4 * q + 3], v1.w, a1);
      a2 = fmaf(x[4 * q], v2.x, a2);
      a2 = fmaf(x[4 * q + 1], v2.y, a2);
      a2 = fmaf(x[4 * q + 2], v2.z, a2);
      a2 = fmaf(x[4 * q + 3], v2.w, a2);
      a3 = fmaf(x[4 * q], v3.x, a3);
      a3 = fmaf(x[4 * q + 1], v3.y, a3);
      a3 = fmaf(x[4 * q + 2], v3.z, a3);
      a3 = fmaf(x[4 * q + 3], v3.w, a3);
    }
    a0 -= en[kb];
    a1 -= en[kb + 256];
    a2 -= en[kb + 512];
    a3 -= en[kb + 768];
    u64 m0 = enc_pair(a0, kb);
    u64 m1 = enc_pair(a1, kb + 256);
    u64 m2 = enc_pair(a2, kb + 512);
    u64 m3 = enc_pair(a3, kb + 768);
    u64 ma = m0 > m1 ? m0 : m1, mb = m2 > m3 ? m2 : m3;
    red[threadIdx.x] = ma > mb ? ma : mb;
    __syncthreads();
    for (int st = 128; st > 0; st >>= 1) {
      if (threadIdx.x < st) {
        u64 o = red[threadIdx.x + st];
        if (o > red[threadIdx.x]) red[threadIdx.x] = o;
      }
      __syncthreads();
    }
    if (threadIdx.x == 0) {
      atomicMax(&cell[i], red[0]);
      __threadfence();                        // max visible before done++
      int old = atomicAdd(&done[i], 1);
      if (old == 7) {                         // last slice: fold k_post in
        u64 v = atomicMax(&cell[i], 0ull);    // atomic read (max with 0)
        idxa[n] = dec_idx(v);
      }
    }
  }
}

// ---- fused scatter (blocks 0..4095) + gather (blocks 4096..5119) ---------
__global__ __launch_bounds__(256) void k_scatter_gather(
    const float* __restrict__ z_e, const float* __restrict__ emb,
    const int* __restrict__ idxa, float* __restrict__ out0,
    float* __restrict__ out1, float* __restrict__ out2,
    float* __restrict__ out4, float* __restrict__ out5) {
  if (blockIdx.x < 4096) {                    // scatter: lane = channel
    int tid = blockIdx.x * 256 + threadIdx.x; // 1M = 16384 tokens x 64 ch
    int n = tid >> 6, c = tid & 63;
    int idx = idxa[n];
    int b = n >> 10, hw = n & 1023;
    float x = z_e[((size_t)b << 16) + ((size_t)c << 10) + hw];
    atomicAdd(out5 + (size_t)idx * 64 + c, OMDF * x);
    if (c == 0) atomicAdd(out4 + idx, OMDF);
  } else {                                    // gather z_q / z_q_st / indices
    int tid = (blockIdx.x - 4096) * 256 + threadIdx.x;  // 262144
    int hw4 = tid & 255;
    int c   = (tid >> 8) & 63;
    int b   = tid >> 14;
    int n0  = (b << 10) + (hw4 << 2);
    size_t off = ((size_t)b << 16) + ((size_t)c << 10) + ((size_t)hw4 << 2);
    float4 z = *(const float4*)(z_e + off);
    int i0 = idxa[n0], i1 = idxa[n0 + 1], i2 = idxa[n0 + 2], i3 = idxa[n0 + 3];
    float4 q;
    q.x = emb[(size_t)i0 * 64 + c];
    q.y = emb[(size_t)i1 * 64 + c];
    q.z = emb[(size_t)i2 * 64 + c];
    q.w = emb[(size_t)i3 * 64 + c];
    float4 st;
    st.x = z.x + (q.x - z.x);
    st.y = z.y + (q.y - z.y);
    st.z = z.z + (q.z - z.z);
    st.w = z.w + (q.w - z.w);
    *(float4*)(out2 + off) = q;
    *(float4*)(out0 + off) = st;
    if (c == 0) {
      float4 f = make_float4((float)i0, (float)i1, (float)i2, (float)i3);
      *(float4*)(out1 + n0) = f;
    }
  }
}

// ---- new_embedding = new_embedding_avg / cs -----------------------------
__global__ __launch_bounds__(256) void k_final(const float* __restrict__ out4,
                                               const float* __restrict__ out5,
                                               const float* __restrict__ nsum,
                                               float* __restrict__ out3) {
  int tid = blockIdx.x * 256 + threadIdx.x;
  int k = tid >> 4;
  double nn  = (double)*nsum + 163.84;        // + 0.01*16384 (counts sum exactly)
  double ncs = (double)out4[k];
  double cs  = (ncs + 1e-5) / (nn + 8192.0 * 1e-5) * nn;
  float inv  = (float)(1.0 / cs);
  float4 v = ((const float4*)out5)[tid];
  v.x *= inv; v.y *= inv; v.z *= inv; v.w *= inv;
  ((float4*)out3)[tid] = v;
}

extern "C" void kernel_launch(void* const* d_in, const int* in_sizes, int n_in,
                              void* d_out, int out_size, void* d_ws, size_t ws_size,
                              hipStream_t stream) {
  const float* z_e    = (const float*)d_in[0];
  const float* emb    = (const float*)d_in[1];
  const float* cs_in  = (const float*)d_in[2];
  const float* avg_in = (const float*)d_in[3];

  float* out  = (float*)d_out;
  float* out0 = out;                    // z_q_st        1048576
  float* out1 = out0 + 1048576;         // indices(f32)  16384
  float* out2 = out1 + 16384;           // z_q           1048576
  float* out3 = out2 + 1048576;         // new_embedding 524288
  float* out4 = out3 + 524288;          // new_cluster   8192
  float* out5 = out4 + 8192;            // new_emb_avg   524288

  char* ws = (char*)d_ws;
  float* en            = (float*)(ws + EN_OFF);
  unsigned char* efrag = (unsigned char*)(ws + EFRAG_OFF);
  u64* best1           = (u64*)(ws + BEST1_OFF);
  float* best2         = (float*)(ws + BEST2_OFF);
  int* idxa            = (int*)(ws + IDX_OFF);
  int* list            = (int*)(ws + LIST_OFF);
  int* cnt             = (int*)(ws + CNT_OFF);
  float* nsum          = (float*)(ws + CNT_OFF + 4);
  u64* cell            = (u64*)(ws + CELL_OFF);
  int* done            = (int*)(ws + DONE_OFF);

  hipMemsetAsync(ws + CNT_OFF, 0, 8, stream);   // cnt + nsum

  k_prep          <<<1032, 256, 0, stream>>>(emb, cs_in, avg_in, en, efrag,
                                             out4, out5, nsum);
  k_argmin_mfma   <<<512,  256, 0, stream>>>(z_e, efrag, en, best1, best2);
  k_resolve       <<<64,   256, 0, stream>>>(best1, best2, idxa, list, cnt,
                                             cell, done);
  k_fixup         <<<2048, 256, 0, stream>>>(z_e, emb, en, list, cnt, cell,
                                             done, idxa);
  k_scatter_gather<<<5120, 256, 0, stream>>>(z_e, emb, idxa, out0, out1, out2,
                                             out4, out5);
  k_final         <<<512,  256, 0, stream>>>(out4, out5, nsum, out3);
}